// Round 16
// baseline (92.330 us; speedup 1.0000x reference)
//
#include <hip/hip_runtime.h>

#define S_LEN 2048
#define NBATCH 32

typedef __bf16 bf16x8 __attribute__((ext_vector_type(8)));
typedef float f32x4 __attribute__((ext_vector_type(4)));
typedef unsigned short bf_t;   // bf16 storage

__device__ __forceinline__ unsigned short f2bf(float f) {
  __bf16 h = (__bf16)f;
  return __builtin_bit_cast(unsigned short, h);
}

#if __has_builtin(__builtin_amdgcn_global_load_lds)
#define USE_GLL 1
#else
#define USE_GLL 0
#endif

// async global->LDS, 16B per lane. ldsbase must be wave-uniform (HW adds lane*16).
__device__ __forceinline__ void load_lds16(const void* g, void* ldsbase) {
#if USE_GLL
  __builtin_amdgcn_global_load_lds(
      (const __attribute__((address_space(1))) unsigned int*)g,
      (__attribute__((address_space(3))) unsigned int*)ldsbase, 16, 0, 0);
#else
  *(int4*)((char*)ldsbase + (threadIdx.x & 63) * 16) =
      *(const int4*)((const char*)g);
#endif
}

#define WAITV8  asm volatile("s_waitcnt vmcnt(8)" ::: "memory")
#define WAITV4  asm volatile("s_waitcnt vmcnt(4)" ::: "memory")
#define WAITV2  asm volatile("s_waitcnt vmcnt(2)" ::: "memory")
#define WAITV0  asm volatile("s_waitcnt vmcnt(0)" ::: "memory")
#define LGKM0   asm volatile("s_waitcnt lgkmcnt(0)" ::: "memory")

// ---------------------------------------------------------------------------
// Fused prep: prep_w1 (blocks 0..639) | prep_w2 (..1919) | fold_bn (block 1920).
__global__ void prep_all(const float* __restrict__ W1, const float* __restrict__ W2,
                         const float* __restrict__ b1, const float* __restrict__ g1,
                         const float* __restrict__ be1, const float* __restrict__ m1,
                         const float* __restrict__ v1,
                         const float* __restrict__ b2, const float* __restrict__ g2,
                         const float* __restrict__ be2, const float* __restrict__ m2,
                         const float* __restrict__ v2,
                         bf_t* __restrict__ wf1, bf_t* __restrict__ wf2,
                         float* __restrict__ abuf, float* __restrict__ zp) {
  const int bid = blockIdx.x;
  if (bid < 1920) {
    // ---- prep_w (conv layers): [256,CIN,5] fp32 -> K-step-major bf16
    const float* w; bf_t* wfm; int idx; int CIN;
    if (bid < 640) { w = W1; wfm = wf1; idx = bid * 256 + threadIdx.x; CIN = 128; }
    else           { w = W2; wfm = wf2; idx = (bid - 640) * 256 + threadIdx.x; CIN = 256; }
    const int TAPS = 5;
    const int j = idx & 7;
    const int l = (idx >> 3) & 63;
    const int f = (idx >> 9) & 7;
    const int wr = (idx >> 12) & 1;
    const int tg = idx >> 13;
    const int co = wr * 128 + f * 16 + (l & 15);
    const int cc = tg / (TAPS * 4);
    const int k = (tg / 4) % TAPS;
    const int q = tg & 3;
    const int ci = cc * 128 + q * 32 + (l >> 4) * 8 + j;
    wfm[idx] = f2bf(w[((size_t)co * CIN + ci) * TAPS + k]);
  } else {
    // ---- fold_bn + zero page
    int c = threadIdx.x;
    if (c < 64) zp[c] = 0.f;
    if (c < 256) {
      float a1 = g1[c] * rsqrtf(v1[c] + 1e-5f);
      abuf[c] = a1;
      abuf[256 + c] = (b1[c] - m1[c]) * a1 + be1[c];
      float a2 = g2[c] * rsqrtf(v2[c] + 1e-5f);
      abuf[512 + c] = a2;
      abuf[768 + c] = (b2[c] - m2[c]) * a2 + be2[c];
    }
  }
}

// ---------------------------------------------------------------------------
// Conv1d as GEMM (R10/R13 K-loop). 2 phases per K-tile, one barrier per phase.
// F32IN=false (conv2): B staged via global_load_lds, counted ladder V8/V8.
// F32IN=true  (conv1): B staged from fp32 x, converted in regs, ds_write to
//   the SAME linear dest GLL would write (swizzled source mapping preserved).
//   B-f32 loads retire in-phase (cvt register dep); A-GLLs issued AFTER them
//   keep depth 2; phase ends = WAITV2 + lgkmcnt(0), tails V0.
// POOL=true: masked fp32 position-sum per co -> hpart (pool commutes with
//   the final 1x1 conv); h2 never materialized.
template <int CIN, int TAPS, bool POOL, bool F32IN>
__device__ __forceinline__ void conv_body(
    const void* __restrict__ xin, const bf_t* __restrict__ wfm,
    const float* __restrict__ alpha, const float* __restrict__ bias,
    const float* __restrict__ zp, bf_t* __restrict__ hout,
    const int* __restrict__ spi, float* __restrict__ hpart) {
  constexpr int HALO = (TAPS - 1) / 2;
  constexpr int P = (CIN / 128) * TAPS * 4;   // K-steps of 32
  constexpr int NKT = P / 2;                  // K-tiles of 64

  __shared__ char smem[131072];

  const int tid = threadIdx.x;
  const int l = tid & 63;
  const int wv = tid >> 6;
  const int wr = wv >> 2;    // 0..1 : co-half (128)
  const int wn = wv & 3;     // 0..3 : pos-quarter (64)
  const int b = blockIdx.x >> 3;
  const int s0 = (blockIdx.x & 7) << 8;
  const int l15 = l & 15;
  const int l4 = l >> 4;
  const int wu16 = (tid - l) * 16;           // wave-uniform dest part

  f32x4 acc[8][4] = {};

  auto STAGE_A = [&](int jt, int sub) {      // 16KB -> A buf (jt&1), sub
    const char* src = (const char*)wfm + (size_t)(2 * jt + sub) * 16384;
    char* dst = smem + (jt & 1) * 32768 + sub * 16384;
    load_lds16(src + tid * 16, dst + wu16);
    load_lds16(src + 8192 + tid * 16, dst + 8192 + wu16);
  };

  auto STAGE_B = [&](int jt, int sub) {      // 16KB im2col -> B buf (jt&1), sub
    const int t = 2 * jt + sub;
    const int k = (t >> 2) % TAPS;
    const int q = t & 3;
    char* dst = smem + 65536 + (jt & 1) * 32768 + sub * 16384;
    const int r0 = tid >> 2;
    const int slot = ((r0 & 3) ^ ((r0 >> 2) & 3)) << 4;
    const int col = ((tid & 3) * 16) ^ slot;       // byte col in 64B quarter-row
    if constexpr (F32IN) {
      // fp32 x [B,S,128]: quarter q, lane's 8 ci -> 32B fp32 at q*128 + col*2
      const char* xrow = (const char*)xin + ((size_t)b * S_LEN * 128) * 4 +
                         q * 128 + col * 2;
#pragma unroll
      for (int h = 0; h < 2; ++h) {
        const int s = s0 + (tid >> 2) + h * 128 - HALO + k;
        const char* src = ((unsigned)s < (unsigned)S_LEN)
            ? xrow + (size_t)s * 512 : ((const char*)zp + col * 2);
        const float4 a = *(const float4*)(src);
        const float4 c = *(const float4*)(src + 16);
        int4 v;
        v.x = (int)((unsigned)f2bf(a.x) | ((unsigned)f2bf(a.y) << 16));
        v.y = (int)((unsigned)f2bf(a.z) | ((unsigned)f2bf(a.w) << 16));
        v.z = (int)((unsigned)f2bf(c.x) | ((unsigned)f2bf(c.y) << 16));
        v.w = (int)((unsigned)f2bf(c.z) | ((unsigned)f2bf(c.w) << 16));
        *(int4*)(dst + h * 8192 + tid * 16) = v;
      }
    } else {
      const int cc = t / (TAPS * 4);
      const char* srcb = (const char*)xin +
          ((size_t)b * S_LEN * CIN + cc * 128 + q * 32) * 2 + col;
#pragma unroll
      for (int h = 0; h < 2; ++h) {
        const int s = s0 + r0 + h * 128 - HALO + k;
        const char* src = ((unsigned)s < (unsigned)S_LEN)
            ? srcb + (size_t)s * (CIN * 2) : ((const char*)zp + col);
        load_lds16(src, dst + h * 8192 + wu16);
      }
    }
  };

  // B fragment read: row r (0..255), sub: 16B at swizzled slot
  auto LDB = [&](const char* Bb, int sub, int r) -> bf16x8 {
    const int slot = (((r & 3) ^ ((r >> 2) & 3)) << 4);
    return *(const bf16x8*)(Bb + sub * 16384 + r * 64 + ((l4 * 16) ^ slot));
  };

  // ---- prologue: K-tile 0 fully landed; K-tile 1 sub0 in flight
  STAGE_A(0, 0); STAGE_A(0, 1); STAGE_B(0, 0); STAGE_B(0, 1);
  WAITV0;
  if constexpr (F32IN) LGKM0;
  STAGE_A(1, 0); STAGE_B(1, 0);
  if constexpr (F32IN) LGKM0;   // drain B(1,0) ds_writes; A(1,0) GLL stays out
  __builtin_amdgcn_s_barrier();

#pragma unroll 1
  for (int j = 0; j < NKT; ++j) {
    const char* Ab = smem + (j & 1) * 32768;
    const char* Bb = smem + 65536 + (j & 1) * 32768;

    // ---- PHASE 0 (sub 0): stage B(j+1,1), A(j+1,1)
    {
      __builtin_amdgcn_s_setprio(1);
      bf16x8 afr[8], bfr[4];
#pragma unroll
      for (int f = 0; f < 8; ++f)
        afr[f] = *(const bf16x8*)(Ab + wr * 8192 + f * 1024 + l * 16);
#pragma unroll
      for (int n = 0; n < 4; ++n)
        bfr[n] = LDB(Bb, 0, wn * 64 + n * 16 + l15);
      if (j + 1 < NKT) { STAGE_B(j + 1, 1); STAGE_A(j + 1, 1); }
#pragma unroll
      for (int f = 0; f < 8; ++f)
#pragma unroll
        for (int n = 0; n < 4; ++n)
          acc[f][n] = __builtin_amdgcn_mfma_f32_16x16x32_bf16(
              afr[f], bfr[n], acc[f][n], 0, 0, 0);
      __builtin_amdgcn_s_setprio(0);
      if constexpr (F32IN) {
        if (j < NKT - 1) { WAITV2; } else { WAITV0; }
        LGKM0;
      } else {
        if (j < NKT - 1) { WAITV8; } else { WAITV0; }
      }
      __builtin_amdgcn_s_barrier();
      __builtin_amdgcn_sched_barrier(0);
    }

    // ---- PHASE 1 (sub 1): stage A(j+2,0), B(j+2,0)
    {
      __builtin_amdgcn_s_setprio(1);
      bf16x8 afr[8], bfr[4];
#pragma unroll
      for (int f = 0; f < 8; ++f)
        afr[f] = *(const bf16x8*)(Ab + 16384 + wr * 8192 + f * 1024 + l * 16);
#pragma unroll
      for (int n = 0; n < 4; ++n)
        bfr[n] = LDB(Bb, 1, wn * 64 + n * 16 + l15);
      if (j + 2 < NKT) { STAGE_A(j + 2, 0); STAGE_B(j + 2, 0); }
#pragma unroll
      for (int f = 0; f < 8; ++f)
#pragma unroll
        for (int n = 0; n < 4; ++n)
          acc[f][n] = __builtin_amdgcn_mfma_f32_16x16x32_bf16(
              afr[f], bfr[n], acc[f][n], 0, 0, 0);
      __builtin_amdgcn_s_setprio(0);
      if constexpr (F32IN) {
        if (j < NKT - 1) { WAITV2; } else { WAITV0; }
        LGKM0;
      } else {
        if (j <= NKT - 3) { WAITV8; } else if (j == NKT - 2) { WAITV4; }
      }
      __builtin_amdgcn_s_barrier();
      __builtin_amdgcn_sched_barrier(0);
    }
  }

  WAITV0;
  __syncthreads();

  if constexpr (!POOL) {
    // ---- epilogue: BN+ReLU -> bf16 -> LDS [sp][512B] swizzled -> coalesced
    const int cobase = wr * 128;
#pragma unroll
    for (int f = 0; f < 8; ++f) {
      const int co0 = cobase + f * 16 + l4 * 4;
      const f32x4 al = *(const f32x4*)(alpha + co0);
      const f32x4 bi = *(const f32x4*)(bias + co0);
#pragma unroll
      for (int n = 0; n < 4; ++n) {
        const int sp = wn * 64 + n * 16 + l15;   // block-local position 0..255
        ushort4 pk;
        pk.x = f2bf(fmaxf(acc[f][n][0] * al[0] + bi[0], 0.f));
        pk.y = f2bf(fmaxf(acc[f][n][1] * al[1] + bi[1], 0.f));
        pk.z = f2bf(fmaxf(acc[f][n][2] * al[2] + bi[2], 0.f));
        pk.w = f2bf(fmaxf(acc[f][n][3] * al[3] + bi[3], 0.f));
        *(ushort4*)(smem + sp * 512 + ((co0 * 2) ^ ((sp & 7) << 4))) = pk;
      }
    }
    __syncthreads();
    char* hb = (char*)hout + ((size_t)(b * S_LEN + s0) * 256) * 2;
#pragma unroll
    for (int k = 0; k < 16; ++k) {
      const int c = tid + k * 512;            // 0..8191 16B-chunks
      const int sp = c >> 5;                  // 32 chunks per 512B row
      const int col = (c & 31) * 16;
      const int4 v = *(const int4*)(smem + sp * 512 + (col ^ ((sp & 7) << 4)));
      *(int4*)(hb + (size_t)sp * 512 + col) = v;
    }
  } else {
    // ---- epilogue: masked fp32 position-sum per co -> hpart[b][pt][256]
    float* red = (float*)smem;                // [8 wv][8 f][4 l4][4 j] = 4KB
    int len = spi[b];
    if (len < 0) len = S_LEN;
    const int cobase = wr * 128;
#pragma unroll
    for (int f = 0; f < 8; ++f) {
      const int co0 = cobase + f * 16 + l4 * 4;
      const f32x4 al = *(const f32x4*)(alpha + co0);
      const f32x4 bi = *(const f32x4*)(bias + co0);
      f32x4 vs = {};
#pragma unroll
      for (int n = 0; n < 4; ++n) {
        const int s = s0 + wn * 64 + n * 16 + l15;
        const float m = (s < len) ? 1.f : 0.f;
        vs[0] += fmaxf(acc[f][n][0] * al[0] + bi[0], 0.f) * m;
        vs[1] += fmaxf(acc[f][n][1] * al[1] + bi[1], 0.f) * m;
        vs[2] += fmaxf(acc[f][n][2] * al[2] + bi[2], 0.f) * m;
        vs[3] += fmaxf(acc[f][n][3] * al[3] + bi[3], 0.f) * m;
      }
#pragma unroll
      for (int d = 1; d < 16; d <<= 1) {
        vs[0] += __shfl_xor(vs[0], d, 64);
        vs[1] += __shfl_xor(vs[1], d, 64);
        vs[2] += __shfl_xor(vs[2], d, 64);
        vs[3] += __shfl_xor(vs[3], d, 64);
      }
      if (l15 == 0) {
        float* rp = red + ((wv * 8 + f) * 4 + l4) * 4;
        rp[0] = vs[0]; rp[1] = vs[1]; rp[2] = vs[2]; rp[3] = vs[3];
      }
    }
    __syncthreads();
    if (tid < 256) {
      const int co = tid;
      const int wrc = co >> 7;
      const int fc = (co >> 4) & 7;
      const int l4c = (co >> 2) & 3;
      const int jc = co & 3;
      float s = 0.f;
#pragma unroll
      for (int w = 0; w < 4; ++w)
        s += red[(((wrc * 4 + w) * 8 + fc) * 4 + l4c) * 4 + jc];
      const int pt = blockIdx.x & 7;
      hpart[((size_t)b * 8 + pt) * 256 + co] = s;
    }
  }
}

__global__ __launch_bounds__(512, 2)
void conv_gemm_L1(const float* __restrict__ xin, const bf_t* __restrict__ wfm,
                  const float* __restrict__ alpha, const float* __restrict__ bias,
                  const float* __restrict__ zp, bf_t* __restrict__ hout) {
  conv_body<128, 5, false, true>(xin, wfm, alpha, bias, zp, hout, nullptr, nullptr);
}

__global__ __launch_bounds__(512, 2)
void conv_gemm_L2(const bf_t* __restrict__ xin, const bf_t* __restrict__ wfm,
                  const float* __restrict__ alpha, const float* __restrict__ bias,
                  const float* __restrict__ zp, const int* __restrict__ spi,
                  float* __restrict__ hpart) {
  conv_body<256, 5, true, false>(xin, wfm, alpha, bias, zp, nullptr, spi, hpart);
}

// ---------------------------------------------------------------------------
// pooled[b][d] = len>0 ? (Wf[d]·S[b] + len*bf[d]) / len : 0,
// where S[b][co] = sum_pt hpart[b][pt][co]. Exact fp32, fixed order.
__global__ void pool_matvec(const float* __restrict__ hpart,
                            const float* __restrict__ Wf,
                            const float* __restrict__ bf_,
                            const int* __restrict__ spi,
                            float* __restrict__ out) {
  __shared__ float S[256];
  const int b = blockIdx.x;
  const int tid = threadIdx.x;   // 128
  for (int c = tid; c < 256; c += 128) {
    float s = 0.f;
#pragma unroll
    for (int pt = 0; pt < 8; ++pt) s += hpart[((size_t)b * 8 + pt) * 256 + c];
    S[c] = s;
  }
  __syncthreads();
  int len = spi[b];
  if (len < 0) len = S_LEN;
  float a = 0.f;
  const float* wrow = Wf + (size_t)tid * 256;
  for (int c = 0; c < 256; ++c) a += wrow[c] * S[c];
  float res = 0.f;
  if (len > 0) res = (a + (float)len * bf_[tid]) / (float)len;
  out[b * 128 + tid] = res;
}

// ---------------------------------------------------------------------------
extern "C" void kernel_launch(void* const* d_in, const int* in_sizes, int n_in,
                              void* d_out, int out_size, void* d_ws, size_t ws_size,
                              hipStream_t stream) {
  (void)in_sizes; (void)n_in; (void)out_size; (void)ws_size;
  const float* x = (const float*)d_in[0];
  const int* spi = (const int*)d_in[1];
  const float* W1 = (const float*)d_in[2];
  const float* b1 = (const float*)d_in[3];
  const float* g1 = (const float*)d_in[4];
  const float* be1 = (const float*)d_in[5];
  const float* m1 = (const float*)d_in[6];
  const float* v1 = (const float*)d_in[7];
  const float* W2 = (const float*)d_in[8];
  const float* b2 = (const float*)d_in[9];
  const float* g2 = (const float*)d_in[10];
  const float* be2 = (const float*)d_in[11];
  const float* m2 = (const float*)d_in[12];
  const float* v2 = (const float*)d_in[13];
  const float* Wf = (const float*)d_in[14];
  const float* bf_ = (const float*)d_in[15];
  float* out = (float*)d_out;

  char* ws = (char*)d_ws;
  float* zp   = (float*)(ws);                        //        256 B zeros
  bf_t* h1    = (bf_t*)(ws + 16781312);              // 33,554,432 B
  bf_t* wf1   = (bf_t*)(ws + 83890176);              //    327,680 B
  bf_t* wf2   = (bf_t*)(ws + 84217856);              //    655,360 B
  float* abuf = (float*)(ws + 84938752);             //      4,096 B
  float* hpart= (float*)(ws + 84942848);             //    262,144 B

  prep_all<<<1921, 256, 0, stream>>>(W1, W2,
                                     b1, g1, be1, m1, v1,
                                     b2, g2, be2, m2, v2,
                                     wf1, wf2, abuf, zp);
  conv_gemm_L1<<<256, 512, 0, stream>>>(x, wf1, abuf, abuf + 256, zp, h1);
  conv_gemm_L2<<<256, 512, 0, stream>>>(h1, wf2, abuf + 512, abuf + 768, zp,
                                        spi, hpart);
  pool_matvec<<<32, 128, 0, stream>>>(hpart, Wf, bf_, spi, out);
}

// Round 17
// 88.233 us; speedup vs baseline: 1.0464x; 1.0464x over previous
//
#include <hip/hip_runtime.h>

#define S_LEN 2048
#define NBATCH 32

typedef __bf16 bf16x8 __attribute__((ext_vector_type(8)));
typedef float f32x4 __attribute__((ext_vector_type(4)));
typedef unsigned short bf_t;   // bf16 storage

__device__ __forceinline__ unsigned short f2bf(float f) {
  __bf16 h = (__bf16)f;
  return __builtin_bit_cast(unsigned short, h);
}

#if __has_builtin(__builtin_amdgcn_global_load_lds)
#define USE_GLL 1
#else
#define USE_GLL 0
#endif

// async global->LDS, 16B per lane. ldsbase must be wave-uniform (HW adds lane*16).
__device__ __forceinline__ void load_lds16(const void* g, void* ldsbase) {
#if USE_GLL
  __builtin_amdgcn_global_load_lds(
      (const __attribute__((address_space(1))) unsigned int*)g,
      (__attribute__((address_space(3))) unsigned int*)ldsbase, 16, 0, 0);
#else
  *(int4*)((char*)ldsbase + (threadIdx.x & 63) * 16) =
      *(const int4*)((const char*)g);
#endif
}

#define WAITV8  asm volatile("s_waitcnt vmcnt(8)" ::: "memory")
#define WAITV4  asm volatile("s_waitcnt vmcnt(4)" ::: "memory")
#define WAITV0  asm volatile("s_waitcnt vmcnt(0)" ::: "memory")

// ---------------------------------------------------------------------------
// Fused prep: convert_x (blocks 0..4095) | prep_w1 (..4735) | prep_w2 (..6015)
// | fold_bn + zero-page (block 6016).
__global__ void prep_all(const float* __restrict__ x,
                         const float* __restrict__ W1, const float* __restrict__ W2,
                         const float* __restrict__ b1, const float* __restrict__ g1,
                         const float* __restrict__ be1, const float* __restrict__ m1,
                         const float* __restrict__ v1,
                         const float* __restrict__ b2, const float* __restrict__ g2,
                         const float* __restrict__ be2, const float* __restrict__ m2,
                         const float* __restrict__ v2,
                         bf_t* __restrict__ xb, bf_t* __restrict__ wf1,
                         bf_t* __restrict__ wf2,
                         float* __restrict__ abuf, float* __restrict__ zp) {
  const int bid = blockIdx.x;
  if (bid < 4096) {
    // ---- convert_x: fp32 [B,S,128] -> bf16, 8 elems/thread
    const size_t i = (size_t)bid * 256 + threadIdx.x;
    const float4 a = ((const float4*)x)[2 * i];
    const float4 c = ((const float4*)x)[2 * i + 1];
    ushort4 o0; o0.x = f2bf(a.x); o0.y = f2bf(a.y); o0.z = f2bf(a.z); o0.w = f2bf(a.w);
    ushort4 o1; o1.x = f2bf(c.x); o1.y = f2bf(c.y); o1.z = f2bf(c.z); o1.w = f2bf(c.w);
    ((ushort4*)xb)[2 * i] = o0;
    ((ushort4*)xb)[2 * i + 1] = o1;
  } else if (bid < 6016) {
    // ---- prep_w (conv layers): [256,CIN,5] fp32 -> K-step-major bf16
    const float* w; bf_t* wfm; int idx; int CIN;
    if (bid < 4736) { w = W1; wfm = wf1; idx = (bid - 4096) * 256 + threadIdx.x; CIN = 128; }
    else            { w = W2; wfm = wf2; idx = (bid - 4736) * 256 + threadIdx.x; CIN = 256; }
    const int TAPS = 5;
    const int j = idx & 7;
    const int l = (idx >> 3) & 63;
    const int f = (idx >> 9) & 7;
    const int wr = (idx >> 12) & 1;
    const int tg = idx >> 13;
    const int co = wr * 128 + f * 16 + (l & 15);
    const int cc = tg / (TAPS * 4);
    const int k = (tg / 4) % TAPS;
    const int q = tg & 3;
    const int ci = cc * 128 + q * 32 + (l >> 4) * 8 + j;
    wfm[idx] = f2bf(w[((size_t)co * CIN + ci) * TAPS + k]);
  } else {
    // ---- fold_bn + zero page
    int c = threadIdx.x;
    if (c < 64) zp[c] = 0.f;
    if (c < 256) {
      float a1 = g1[c] * rsqrtf(v1[c] + 1e-5f);
      abuf[c] = a1;
      abuf[256 + c] = (b1[c] - m1[c]) * a1 + be1[c];
      float a2 = g2[c] * rsqrtf(v2[c] + 1e-5f);
      abuf[512 + c] = a2;
      abuf[768 + c] = (b2[c] - m2[c]) * a2 + be2[c];
    }
  }
}

// ---------------------------------------------------------------------------
// Conv1d as GEMM (R10/R13 K-loop — best measured, untouched). 2 phases per
// K-tile, one barrier per phase, counted-vmcnt ladder V8/V8, tail V0/V4.
// POOL=false: BN+ReLU -> bf16 -> LDS-transpose -> coalesced h stores.
// POOL=true : BN+ReLU kept fp32; masked position-sum per co (pool commutes
//             with the 1x1 conv) -> hpart[b][pt][256], h2 never materialized.
template <int CIN, int TAPS, bool POOL>
__device__ __forceinline__ void conv_body(
    const bf_t* __restrict__ xin, const bf_t* __restrict__ wfm,
    const float* __restrict__ alpha, const float* __restrict__ bias,
    const float* __restrict__ zp, bf_t* __restrict__ hout,
    const int* __restrict__ spi, float* __restrict__ hpart) {
  constexpr int HALO = (TAPS - 1) / 2;
  constexpr int P = (CIN / 128) * TAPS * 4;   // K-steps of 32
  constexpr int NKT = P / 2;                  // K-tiles of 64

  __shared__ char smem[131072];

  const int tid = threadIdx.x;
  const int l = tid & 63;
  const int wv = tid >> 6;
  const int wr = wv >> 2;    // 0..1 : co-half (128)
  const int wn = wv & 3;     // 0..3 : pos-quarter (64)
  const int b = blockIdx.x >> 3;
  const int s0 = (blockIdx.x & 7) << 8;
  const int l15 = l & 15;
  const int l4 = l >> 4;
  const int wu16 = (tid - l) * 16;           // wave-uniform dest part

  f32x4 acc[8][4] = {};

  auto STAGE_A = [&](int jt, int sub) {      // 16KB -> A buf (jt&1), sub
    const char* src = (const char*)wfm + (size_t)(2 * jt + sub) * 16384;
    char* dst = smem + (jt & 1) * 32768 + sub * 16384;
    load_lds16(src + tid * 16, dst + wu16);
    load_lds16(src + 8192 + tid * 16, dst + 8192 + wu16);
  };

  auto STAGE_B = [&](int jt, int sub) {      // 16KB im2col -> B buf (jt&1), sub
    const int t = 2 * jt + sub;
    const int cc = t / (TAPS * 4);
    const int k = (t >> 2) % TAPS;
    const int q = t & 3;
    char* dst = smem + 65536 + (jt & 1) * 32768 + sub * 16384;
    const int r0 = tid >> 2;
    const int slot = ((r0 & 3) ^ ((r0 >> 2) & 3)) << 4;
    const char* srcb = (const char*)xin +
        ((size_t)b * S_LEN * CIN + cc * 128 + q * 32) * 2 +
        (((tid & 3) * 16) ^ slot);
    {
      const int s = s0 + r0 - HALO + k;
      const char* src = ((unsigned)s < (unsigned)S_LEN)
          ? srcb + (size_t)s * (CIN * 2) : ((const char*)zp + (((tid & 3) * 16) ^ slot));
      load_lds16(src, dst + wu16);
    }
    {
      const int s = s0 + r0 + 128 - HALO + k;
      const char* src = ((unsigned)s < (unsigned)S_LEN)
          ? srcb + (size_t)s * (CIN * 2) : ((const char*)zp + (((tid & 3) * 16) ^ slot));
      load_lds16(src, dst + 8192 + wu16);
    }
  };

  // B fragment read: row r (0..255), sub: 16B at swizzled slot
  auto LDB = [&](const char* Bb, int sub, int r) -> bf16x8 {
    const int slot = (((r & 3) ^ ((r >> 2) & 3)) << 4);
    return *(const bf16x8*)(Bb + sub * 16384 + r * 64 + ((l4 * 16) ^ slot));
  };

  // ---- prologue: K-tile 0 fully landed; K-tile 1 sub0 in flight (4 GLL)
  STAGE_A(0, 0); STAGE_A(0, 1); STAGE_B(0, 0); STAGE_B(0, 1);
  WAITV0;
  STAGE_A(1, 0); STAGE_B(1, 0);
  __builtin_amdgcn_s_barrier();

#pragma unroll 1
  for (int j = 0; j < NKT; ++j) {
    const char* Ab = smem + (j & 1) * 32768;
    const char* Bb = smem + 65536 + (j & 1) * 32768;

    // ---- PHASE 0 (sub 0)
    {
      __builtin_amdgcn_s_setprio(1);
      bf16x8 afr[8], bfr[4];
#pragma unroll
      for (int f = 0; f < 8; ++f)
        afr[f] = *(const bf16x8*)(Ab + wr * 8192 + f * 1024 + l * 16);
#pragma unroll
      for (int n = 0; n < 4; ++n)
        bfr[n] = LDB(Bb, 0, wn * 64 + n * 16 + l15);
      if (j + 1 < NKT) { STAGE_B(j + 1, 1); STAGE_A(j + 1, 1); }
#pragma unroll
      for (int f = 0; f < 8; ++f)
#pragma unroll
        for (int n = 0; n < 4; ++n)
          acc[f][n] = __builtin_amdgcn_mfma_f32_16x16x32_bf16(
              afr[f], bfr[n], acc[f][n], 0, 0, 0);
      __builtin_amdgcn_s_setprio(0);
      if (j < NKT - 1) { WAITV8; } else { WAITV0; }
      __builtin_amdgcn_s_barrier();
      __builtin_amdgcn_sched_barrier(0);
    }

    // ---- PHASE 1 (sub 1)
    {
      __builtin_amdgcn_s_setprio(1);
      bf16x8 afr[8], bfr[4];
#pragma unroll
      for (int f = 0; f < 8; ++f)
        afr[f] = *(const bf16x8*)(Ab + 16384 + wr * 8192 + f * 1024 + l * 16);
#pragma unroll
      for (int n = 0; n < 4; ++n)
        bfr[n] = LDB(Bb, 1, wn * 64 + n * 16 + l15);
      if (j + 2 < NKT) { STAGE_A(j + 2, 0); STAGE_B(j + 2, 0); }
#pragma unroll
      for (int f = 0; f < 8; ++f)
#pragma unroll
        for (int n = 0; n < 4; ++n)
          acc[f][n] = __builtin_amdgcn_mfma_f32_16x16x32_bf16(
              afr[f], bfr[n], acc[f][n], 0, 0, 0);
      __builtin_amdgcn_s_setprio(0);
      if (j <= NKT - 3) { WAITV8; } else if (j == NKT - 2) { WAITV4; }
      __builtin_amdgcn_s_barrier();
      __builtin_amdgcn_sched_barrier(0);
    }
  }

  WAITV0;
  __syncthreads();

  if constexpr (!POOL) {
    // ---- epilogue: BN+ReLU -> bf16 -> LDS [sp][512B] swizzled -> coalesced
    const int cobase = wr * 128;
#pragma unroll
    for (int f = 0; f < 8; ++f) {
      const int co0 = cobase + f * 16 + l4 * 4;
      const f32x4 al = *(const f32x4*)(alpha + co0);
      const f32x4 bi = *(const f32x4*)(bias + co0);
#pragma unroll
      for (int n = 0; n < 4; ++n) {
        const int sp = wn * 64 + n * 16 + l15;   // block-local position 0..255
        ushort4 pk;
        pk.x = f2bf(fmaxf(acc[f][n][0] * al[0] + bi[0], 0.f));
        pk.y = f2bf(fmaxf(acc[f][n][1] * al[1] + bi[1], 0.f));
        pk.z = f2bf(fmaxf(acc[f][n][2] * al[2] + bi[2], 0.f));
        pk.w = f2bf(fmaxf(acc[f][n][3] * al[3] + bi[3], 0.f));
        *(ushort4*)(smem + sp * 512 + ((co0 * 2) ^ ((sp & 7) << 4))) = pk;
      }
    }
    __syncthreads();
    char* hb = (char*)hout + ((size_t)(b * S_LEN + s0) * 256) * 2;
#pragma unroll
    for (int k = 0; k < 16; ++k) {
      const int c = tid + k * 512;            // 0..8191 16B-chunks
      const int sp = c >> 5;                  // 32 chunks per 512B row
      const int col = (c & 31) * 16;
      const int4 v = *(const int4*)(smem + sp * 512 + (col ^ ((sp & 7) << 4)));
      *(int4*)(hb + (size_t)sp * 512 + col) = v;
    }
  } else {
    // ---- epilogue: masked fp32 position-sum per co -> hpart[b][pt][256].
    // Pool commutes with the final 1x1 conv; h2 is never materialized.
    float* red = (float*)smem;                // [8 wv][8 f][4 l4][4 j] = 4KB
    int len = spi[b];
    if (len < 0) len = S_LEN;
    const int cobase = wr * 128;
#pragma unroll
    for (int f = 0; f < 8; ++f) {
      const int co0 = cobase + f * 16 + l4 * 4;
      const f32x4 al = *(const f32x4*)(alpha + co0);
      const f32x4 bi = *(const f32x4*)(bias + co0);
      f32x4 vs = {};
#pragma unroll
      for (int n = 0; n < 4; ++n) {
        const int s = s0 + wn * 64 + n * 16 + l15;
        const float m = (s < len) ? 1.f : 0.f;
        vs[0] += fmaxf(acc[f][n][0] * al[0] + bi[0], 0.f) * m;
        vs[1] += fmaxf(acc[f][n][1] * al[1] + bi[1], 0.f) * m;
        vs[2] += fmaxf(acc[f][n][2] * al[2] + bi[2], 0.f) * m;
        vs[3] += fmaxf(acc[f][n][3] * al[3] + bi[3], 0.f) * m;
      }
#pragma unroll
      for (int d = 1; d < 16; d <<= 1) {
        vs[0] += __shfl_xor(vs[0], d, 64);
        vs[1] += __shfl_xor(vs[1], d, 64);
        vs[2] += __shfl_xor(vs[2], d, 64);
        vs[3] += __shfl_xor(vs[3], d, 64);
      }
      if (l15 == 0) {
        float* rp = red + ((wv * 8 + f) * 4 + l4) * 4;
        rp[0] = vs[0]; rp[1] = vs[1]; rp[2] = vs[2]; rp[3] = vs[3];
      }
    }
    __syncthreads();
    if (tid < 256) {
      const int co = tid;
      const int wrc = co >> 7;
      const int fc = (co >> 4) & 7;
      const int l4c = (co >> 2) & 3;
      const int jc = co & 3;
      float s = 0.f;
#pragma unroll
      for (int w = 0; w < 4; ++w)
        s += red[(((wrc * 4 + w) * 8 + fc) * 4 + l4c) * 4 + jc];
      const int pt = blockIdx.x & 7;
      hpart[((size_t)b * 8 + pt) * 256 + co] = s;
    }
  }
}

__global__ __launch_bounds__(512, 2)
void conv_gemm_L1(const bf_t* __restrict__ xin, const bf_t* __restrict__ wfm,
                  const float* __restrict__ alpha, const float* __restrict__ bias,
                  const float* __restrict__ zp, bf_t* __restrict__ hout) {
  conv_body<128, 5, false>(xin, wfm, alpha, bias, zp, hout, nullptr, nullptr);
}

__global__ __launch_bounds__(512, 2)
void conv_gemm_L2(const bf_t* __restrict__ xin, const bf_t* __restrict__ wfm,
                  const float* __restrict__ alpha, const float* __restrict__ bias,
                  const float* __restrict__ zp, const int* __restrict__ spi,
                  float* __restrict__ hpart) {
  conv_body<256, 5, true>(xin, wfm, alpha, bias, zp, nullptr, spi, hpart);
}

// ---------------------------------------------------------------------------
// pooled[b][d] = len>0 ? (Wf[d]·S[b] + len*bf[d]) / len : 0,
// where S[b][co] = sum_pt hpart[b][pt][co]. Exact fp32, fixed order.
__global__ void pool_matvec(const float* __restrict__ hpart,
                            const float* __restrict__ Wf,
                            const float* __restrict__ bf_,
                            const int* __restrict__ spi,
                            float* __restrict__ out) {
  __shared__ float S[256];
  const int b = blockIdx.x;
  const int tid = threadIdx.x;   // 128
  for (int c = tid; c < 256; c += 128) {
    float s = 0.f;
#pragma unroll
    for (int pt = 0; pt < 8; ++pt) s += hpart[((size_t)b * 8 + pt) * 256 + c];
    S[c] = s;
  }
  __syncthreads();
  int len = spi[b];
  if (len < 0) len = S_LEN;
  float a = 0.f;
  const float* wrow = Wf + (size_t)tid * 256;
  for (int c = 0; c < 256; ++c) a += wrow[c] * S[c];
  float res = 0.f;
  if (len > 0) res = (a + (float)len * bf_[tid]) / (float)len;
  out[b * 128 + tid] = res;
}

// ---------------------------------------------------------------------------
extern "C" void kernel_launch(void* const* d_in, const int* in_sizes, int n_in,
                              void* d_out, int out_size, void* d_ws, size_t ws_size,
                              hipStream_t stream) {
  (void)in_sizes; (void)n_in; (void)out_size; (void)ws_size;
  const float* x = (const float*)d_in[0];
  const int* spi = (const int*)d_in[1];
  const float* W1 = (const float*)d_in[2];
  const float* b1 = (const float*)d_in[3];
  const float* g1 = (const float*)d_in[4];
  const float* be1 = (const float*)d_in[5];
  const float* m1 = (const float*)d_in[6];
  const float* v1 = (const float*)d_in[7];
  const float* W2 = (const float*)d_in[8];
  const float* b2 = (const float*)d_in[9];
  const float* g2 = (const float*)d_in[10];
  const float* be2 = (const float*)d_in[11];
  const float* m2 = (const float*)d_in[12];
  const float* v2 = (const float*)d_in[13];
  const float* Wf = (const float*)d_in[14];
  const float* bf_ = (const float*)d_in[15];
  float* out = (float*)d_out;

  char* ws = (char*)d_ws;
  float* zp   = (float*)(ws);                        //        256 B zeros
  bf_t* xb    = (bf_t*)(ws + 4096);                  // 16,777,216 B
  bf_t* h1    = (bf_t*)(ws + 16781312);              // 33,554,432 B
  bf_t* wf1   = (bf_t*)(ws + 83890176);              //    327,680 B
  bf_t* wf2   = (bf_t*)(ws + 84217856);              //    655,360 B
  float* abuf = (float*)(ws + 84938752);             //      4,096 B
  float* hpart= (float*)(ws + 84942848);             //    262,144 B

  prep_all<<<6017, 256, 0, stream>>>(x, W1, W2,
                                     b1, g1, be1, m1, v1,
                                     b2, g2, be2, m2, v2,
                                     xb, wf1, wf2, abuf, zp);
  conv_gemm_L1<<<256, 512, 0, stream>>>(xb, wf1, abuf, abuf + 256, zp, h1);
  conv_gemm_L2<<<256, 512, 0, stream>>>(h1, wf2, abuf + 512, abuf + 768, zp,
                                        spi, hpart);
  pool_matvec<<<32, 128, 0, stream>>>(hpart, Wf, bf_, spi, out);
}